// Round 17
// baseline (2420.254 us; speedup 1.0000x reference)
//
#include <hip/hip_runtime.h>
#include <math.h>

#define DD 1024
#define HH 4096
#define EE 23
#define KK 3
#define NTOK 8192
#define BM 256
#define BN 128
#define BK 32
#define MAXROWS 38656    // 8192 shared + 24576 routed + per-expert pad(<=23*255), 256-aligned
#define MAXTILES 152     // 32 shared + <=119 expert tiles + slack

typedef unsigned short u16;
typedef __attribute__((ext_vector_type(8))) short bf16x8;
typedef __attribute__((ext_vector_type(8))) unsigned short u16x8;
typedef __attribute__((ext_vector_type(4))) float f32x4;
typedef __attribute__((address_space(3))) unsigned int lds_u32;
typedef const __attribute__((address_space(1))) unsigned int gbl_u32;

struct Tile { int rowStart; int validEnd; int expert; };

__device__ __forceinline__ u16 f2bf(float f) {
    unsigned int u = __float_as_uint(f);
    unsigned int r = 0x7FFFu + ((u >> 16) & 1u);
    return (u16)((u + r) >> 16);
}
// exact-GELU via Abramowitz-Stegun 7.1.26 erf (max |err| 1.5e-7).
__device__ __forceinline__ float gelu_exact(float x) {
    float z = x * 0.70710678118654752f;
    float a = fabsf(z);
    float t = __builtin_amdgcn_rcpf(1.0f + 0.3275911f * a);
    float e = __builtin_amdgcn_exp2f(-a * a * 1.4426950408889634f);
    float p = t * (0.254829592f + t * (-0.284496736f + t * (1.421413741f +
              t * (-1.453152027f + t * 1.061405429f))));
    float er = 1.0f - p * e;
    er = (z < 0.0f) ? -er : er;
    return 0.5f * x * (1.0f + er);
}
// async global->LDS, 16B per lane; offset literal MUST stay 0 (r7 NaN lesson).
__device__ __forceinline__ void gl2lds16(const u16* g, u16* l) {
    __builtin_amdgcn_global_load_lds((gbl_u32*)g, (lds_u32*)l, 16, 0, 0);
}

// ---- W transpose: fp32 [R][C] -> bf16 [C][R], 64x128 tiles, 16B stores ----
// which==1: W1 (runs right before gemm1 -> w1t L3-fresh; r15: -70us);
// which==0: W2 (runs between gemm1 and gemm2). fp32 reads NON-TEMPORAL.
__global__ __launch_bounds__(256) void k_transpose(
    const float* __restrict__ WE, u16* __restrict__ wEt,
    const float* __restrict__ WS, u16* __restrict__ wSt, int which) {
    __shared__ float tile[64][129];
    int f = blockIdx.y, t = threadIdx.x, b = blockIdx.x;
    const float* src; u16* dst; int R, C, ct, rt;
    if (which) {
        R = DD; C = HH;
        ct = b & 31; rt = b >> 5;
    } else {
        R = HH; C = DD;
        ct = b & 7; rt = b >> 3;
    }
    if (f == EE) { src = WS; dst = wSt; }
    else { size_t base = (size_t)f * DD * HH; src = WE + base; dst = wEt + base; }
    int r0 = rt * 64, c0 = ct * 128;
#pragma unroll
    for (int i = 0; i < 8; i++) {
        int r = i * 8 + (t >> 5);
        int c = (t & 31) * 4;
        f32x4 v = __builtin_nontemporal_load(
            reinterpret_cast<const f32x4*>(&src[(size_t)(r0 + r) * C + c0 + c]));
        tile[r][c] = v.x; tile[r][c + 1] = v.y; tile[r][c + 2] = v.z; tile[r][c + 3] = v.w;
    }
    __syncthreads();
#pragma unroll
    for (int j = 0; j < 4; j++) {
        int c = j * 32 + (t >> 3);
        int r8 = (t & 7) * 8;
        u16x8 o;
#pragma unroll
        for (int k = 0; k < 8; k++) o[k] = f2bf(tile[r8 + k][c]);
        *reinterpret_cast<u16x8*>(&dst[(size_t)(c0 + c) * R + r0 + r8]) = o;
    }
}

// -------- gating: sigmoid(x@gW+gb), top3, counts/Psum; also emits xbf --------
__global__ void k_gate(const float* __restrict__ x, const float* __restrict__ gW,
                       const float* __restrict__ gb, const float* __restrict__ ebias,
                       int* __restrict__ topi, float* __restrict__ topw,
                       int* __restrict__ counts, float* __restrict__ psum,
                       u16* __restrict__ xbf) {
    int tok = blockIdx.x, t = threadIdx.x;
    float acc[EE];
#pragma unroll
    for (int e = 0; e < EE; e++) acc[e] = 0.f;
    float4 xv = reinterpret_cast<const float4*>(x + (size_t)tok * DD)[t];
    ushort4 xo;
    xo.x = f2bf(xv.x); xo.y = f2bf(xv.y); xo.z = f2bf(xv.z); xo.w = f2bf(xv.w);
    reinterpret_cast<ushort4*>(xbf + (size_t)tok * DD)[t] = xo;
    float xs[4] = {xv.x, xv.y, xv.z, xv.w};
#pragma unroll
    for (int i = 0; i < 4; i++) {
        const float* grow = gW + (size_t)(t * 4 + i) * EE;
        float xd = xs[i];
#pragma unroll
        for (int e = 0; e < EE; e++) acc[e] += xd * grow[e];
    }
#pragma unroll
    for (int e = 0; e < EE; e++) {
        float v = acc[e];
        for (int off = 32; off; off >>= 1) v += __shfl_down(v, off);
        acc[e] = v;
    }
    __shared__ float part[4][EE];
    __shared__ float gwS[EE], scoreS[EE], rowsumS;
    int wave = t >> 6, lane = t & 63;
    if (lane == 0) {
#pragma unroll
        for (int e = 0; e < EE; e++) part[wave][e] = acc[e];
    }
    __syncthreads();
    if (t < EE) {
        float v = part[0][t] + part[1][t] + part[2][t] + part[3][t] + gb[t];
        float g = 1.f / (1.f + expf(-v));
        gwS[t] = g;
        scoreS[t] = g + ebias[t];
    }
    __syncthreads();
    if (t == 0) {
        int i0 = 0, i1 = -1, i2 = -1;
        float s0 = -1e30f, s1 = -1e30f, s2 = -1e30f;
        for (int e = 0; e < EE; e++) {
            float s = scoreS[e];
            if (s > s0)      { s2 = s1; i2 = i1; s1 = s0; i1 = i0; s0 = s; i0 = e; }
            else if (s > s1) { s2 = s1; i2 = i1; s1 = s;  i1 = e; }
            else if (s > s2) { s2 = s;  i2 = e; }
        }
        float w0 = gwS[i0], w1 = gwS[i1], w2 = gwS[i2];
        float wsum = w0 + w1 + w2;
        topi[tok * 3] = i0; topi[tok * 3 + 1] = i1; topi[tok * 3 + 2] = i2;
        topw[tok * 3] = w0 / wsum; topw[tok * 3 + 1] = w1 / wsum; topw[tok * 3 + 2] = w2 / wsum;
        atomicAdd(&counts[i0], 1); atomicAdd(&counts[i1], 1); atomicAdd(&counts[i2], 1);
        float rs = 0.f;
        for (int e = 0; e < EE; e++) rs += gwS[e];
        rowsumS = rs;
    }
    __syncthreads();
    if (t < EE) atomicAdd(&psum[t], gwS[t] / rowsumS);
}

// ---------------- offsets, tile table, aux loss (single thread) ----------------
__global__ void k_setup(const int* __restrict__ counts, const float* __restrict__ psum,
                        int* __restrict__ offs, Tile* __restrict__ tiles,
                        int* __restrict__ numTiles, float* __restrict__ out_aux) {
    if (threadIdx.x != 0 || blockIdx.x != 0) return;
    int nt = 0;
    for (int i = 0; i < NTOK / BM; i++) {   // 32 shared-expert tiles (256 rows each)
        tiles[nt].rowStart = i * BM; tiles[nt].validEnd = NTOK; tiles[nt].expert = EE; nt++;
    }
    int base = NTOK;
    for (int e = 0; e < EE; e++) {
        offs[e] = base;
        int c = counts[e];
        int ntile = (c + BM - 1) / BM;
        for (int i = 0; i < ntile; i++) {
            tiles[nt].rowStart = base + i * BM; tiles[nt].validEnd = base + c; tiles[nt].expert = e; nt++;
        }
        base += ntile * BM;   // per-expert regions 256-aligned
    }
    numTiles[0] = nt;
    float aux = 0.f;
    for (int e = 0; e < EE; e++)
        aux += (psum[e] / (float)NTOK) * ((float)EE * (float)counts[e] / ((float)KK * (float)NTOK));
    out_aux[0] = aux;
}

// ---------------- scatter tokens into expert row slots ----------------
__global__ void k_scatter(const int* __restrict__ topi, const float* __restrict__ topw,
                          const int* __restrict__ offs, int* __restrict__ cursor,
                          int* __restrict__ rowTok, float* __restrict__ rowW) {
    int tok = blockIdx.x * blockDim.x + threadIdx.x;
    if (tok >= NTOK) return;
    rowTok[tok] = tok; rowW[tok] = 1.0f;
    for (int k = 0; k < KK; k++) {
        int e = topi[tok * 3 + k];
        int pos = atomicAdd(&cursor[e], 1);
        int slot = offs[e] + pos;
        rowTok[slot] = tok; rowW[slot] = topw[tok * 3 + k];
    }
}

// --- GEMM1: H = gelu(X @ W1 + b1)  [256x128 tile, SAME 2-barrier loop, BK=32] ---
__global__ __launch_bounds__(256) void k_gemm1(
    const u16* __restrict__ xbf, const u16* __restrict__ w1t, const u16* __restrict__ sw1t,
    const float* __restrict__ b1, const float* __restrict__ sb1,
    const int* __restrict__ rowTok, const Tile* __restrict__ tiles,
    const int* __restrict__ numTiles, u16* __restrict__ hbuf, int chunkBase, int hrows) {
    // XCD-bijective chunk -> supertile decode (4 tiles x 4 panels = 3MB, L2-fit)
    const int T = MAXTILES * (HH / BN);          // 152*32 = 4864, %8==0
    int b = blockIdx.x;
    int key = (b & 7) * (T >> 3) + (b >> 3);     // 0..4863, bijective
    int sid = key >> 4, wi = key & 15;           // 16 blocks per supertile
    int tg = sid >> 3, pg = sid & 7;             // 38 tile-groups x 8 panel-groups
    int ti = tg * 4 + (wi >> 2);                 // 0..151
    int p  = pg * 4 + (wi & 3);                  // 0..31
    if (ti >= numTiles[0]) return;
    Tile tl = tiles[ti];
    if (tl.rowStart < chunkBase || tl.rowStart >= chunkBase + hrows) return;
    int e = tl.expert;
    const u16* wbase = (e == EE) ? sw1t : (w1t + (size_t)e * HH * DD);
    const float* bias = (e == EE) ? sb1 : (b1 + (size_t)e * HH);
    int hbase = p * BN;
    int t = threadIdx.x, lane = t & 63, wv = t >> 6, wr = wv >> 1, wc = wv & 1;

    __shared__ u16 As[BM * BK];   // [256][32] linear, 64B rows (conflict-safe), 16KB
    __shared__ u16 Bs[BN * BK];   // [128][32], 8KB

    // staging: A issue i covers rows i*64 + (t>>2), col (t&3)*8; dest t*16B + i*4KB
    int r64 = t >> 2;
    int c8 = (t & 3) * 8;
    const u16* ap[4];
#pragma unroll
    for (int i = 0; i < 4; i++) {
        int s = tl.rowStart + i * 64 + r64;
        int tok2 = (s < tl.validEnd) ? rowTok[s] : 0;
        ap[i] = xbf + (size_t)tok2 * DD + c8;
    }
    const u16* g0 = wbase + (size_t)(hbase + r64) * DD + c8;
    const u16* g1 = wbase + (size_t)(hbase + 64 + r64) * DD + c8;
    u16* lA = &As[t * 8];
    u16* lB = &Bs[t * 8];

    f32x4 acc[8][4];
#pragma unroll
    for (int m = 0; m < 8; m++)
#pragma unroll
        for (int n = 0; n < 4; n++) acc[m][n] = (f32x4){0.f, 0.f, 0.f, 0.f};

    for (int kt = 0; kt < DD / BK; kt++) {       // 32 iterations
        __syncthreads();                         // all waves done reading previous tile
#pragma unroll
        for (int i = 0; i < 4; i++) { gl2lds16(ap[i], lA + i * 2048); ap[i] += BK; }
        gl2lds16(g0, lB); gl2lds16(g1, lB + 2048);
        g0 += BK; g1 += BK;
        __syncthreads();                         // drains vmcnt(0): tile ready
        bf16x8 af[8], bw[4];
        int kc = (lane >> 4) * 8;
#pragma unroll
        for (int m = 0; m < 8; m++)
            af[m] = *reinterpret_cast<const bf16x8*>(&As[(wr * 128 + m * 16 + (lane & 15)) * BK + kc]);
#pragma unroll
        for (int n = 0; n < 4; n++)
            bw[n] = *reinterpret_cast<const bf16x8*>(&Bs[(wc * 64 + n * 16 + (lane & 15)) * BK + kc]);
#pragma unroll
        for (int m = 0; m < 8; m++)
#pragma unroll
            for (int n = 0; n < 4; n++)
                acc[m][n] = __builtin_amdgcn_mfma_f32_16x16x32_bf16(af[m], bw[n], acc[m][n], 0, 0, 0);
    }

    // epilogue: NON-TEMPORAL hbuf stores (protect L3-resident w1t)
#pragma unroll
    for (int m = 0; m < 8; m++) {
        int rowl = wr * 128 + m * 16 + (lane >> 4) * 4;
#pragma unroll
        for (int r = 0; r < 4; r++) {
            int slotr = tl.rowStart + rowl + r;
            bool valid = slotr < tl.validEnd;
            size_t hoff = (size_t)(slotr - chunkBase) * HH;
#pragma unroll
            for (int n = 0; n < 4; n++) {
                int col = hbase + wc * 64 + n * 16 + (lane & 15);
                float v = acc[m][n][r] + bias[col];
                u16 o = valid ? f2bf(gelu_exact(v)) : (u16)0;
                __builtin_nontemporal_store(o, &hbuf[hoff + col]);
            }
        }
    }
}

// --- GEMM2: out += w * (H @ W2 + b2)  [256x128 tile, SAME 2-barrier loop] ---
__global__ __launch_bounds__(256) void k_gemm2(
    const u16* __restrict__ hbuf, const u16* __restrict__ w2t, const u16* __restrict__ sw2t,
    const float* __restrict__ b2, const float* __restrict__ sb2,
    const int* __restrict__ rowTok, const float* __restrict__ rowW,
    const Tile* __restrict__ tiles, const int* __restrict__ numTiles,
    float* __restrict__ out, int chunkBase, int hrows) {
    // XCD-bijective chunk -> supertile decode (2 tiles x 2 panels)
    const int T = MAXTILES * (DD / BN);          // 152*8 = 1216, %8==0
    int b = blockIdx.x;
    int key = (b & 7) * (T >> 3) + (b >> 3);     // 0..1215, bijective
    int sid = key >> 2, wi = key & 3;            // 4 blocks per supertile
    int tg = sid >> 2, pg = sid & 3;             // 76 tile-groups x 4 panel-groups
    int ti = tg * 2 + (wi >> 1);                 // 0..151
    int p  = pg * 2 + (wi & 1);                  // 0..7
    if (ti >= numTiles[0]) return;
    Tile tl = tiles[ti];
    if (tl.rowStart < chunkBase || tl.rowStart >= chunkBase + hrows) return;
    int e = tl.expert;
    const u16* wbase = (e == EE) ? sw2t : (w2t + (size_t)e * DD * HH);
    const float* bias = (e == EE) ? sb2 : (b2 + (size_t)e * DD);
    int dbase = p * BN;
    int t = threadIdx.x, lane = t & 63, wv = t >> 6, wr = wv >> 1, wc = wv & 1;

    __shared__ u16 As[BM * BK];
    __shared__ u16 Bs[BN * BK];

    int r64 = t >> 2;
    int c8 = (t & 3) * 8;
    const u16* ap[4];
#pragma unroll
    for (int i = 0; i < 4; i++)
        ap[i] = hbuf + (size_t)(tl.rowStart - chunkBase + i * 64 + r64) * HH + c8;
    const u16* g0 = wbase + (size_t)(dbase + r64) * HH + c8;
    const u16* g1 = wbase + (size_t)(dbase + 64 + r64) * HH + c8;
    u16* lA = &As[t * 8];
    u16* lB = &Bs[t * 8];

    f32x4 acc[8][4];
#pragma unroll
    for (int m = 0; m < 8; m++)
#pragma unroll
        for (int n = 0; n < 4; n++) acc[m][n] = (f32x4){0.f, 0.f, 0.f, 0.f};

    for (int kt = 0; kt < HH / BK; kt++) {       // 128 iterations
        __syncthreads();
#pragma unroll
        for (int i = 0; i < 4; i++) { gl2lds16(ap[i], lA + i * 2048); ap[i] += BK; }
        gl2lds16(g0, lB); gl2lds16(g1, lB + 2048);
        g0 += BK; g1 += BK;
        __syncthreads();
        bf16x8 af[8], bw[4];
        int kc = (lane >> 4) * 8;
#pragma unroll
        for (int m = 0; m < 8; m++)
            af[m] = *reinterpret_cast<const bf16x8*>(&As[(wr * 128 + m * 16 + (lane & 15)) * BK + kc]);
#pragma unroll
        for (int n = 0; n < 4; n++)
            bw[n] = *reinterpret_cast<const bf16x8*>(&Bs[(wc * 64 + n * 16 + (lane & 15)) * BK + kc]);
#pragma unroll
        for (int m = 0; m < 8; m++)
#pragma unroll
            for (int n = 0; n < 4; n++)
                acc[m][n] = __builtin_amdgcn_mfma_f32_16x16x32_bf16(af[m], bw[n], acc[m][n], 0, 0, 0);
    }

#pragma unroll
    for (int m = 0; m < 8; m++) {
        int rowl = wr * 128 + m * 16 + (lane >> 4) * 4;
#pragma unroll
        for (int r = 0; r < 4; r++) {
            int slotr = tl.rowStart + rowl + r;
            if (slotr < tl.validEnd) {
                int tok2 = rowTok[slotr];
                float wgt = rowW[slotr];
                float* orow = out + (size_t)tok2 * DD;
#pragma unroll
                for (int n = 0; n < 4; n++) {
                    int col = dbase + wc * 64 + n * 16 + (lane & 15);
                    float v = acc[m][n][r] + bias[col];
                    atomicAdd(&orow[col], wgt * v);
                }
            }
        }
    }
}

extern "C" void kernel_launch(void* const* d_in, const int* in_sizes, int n_in,
                              void* d_out, int out_size, void* d_ws, size_t ws_size,
                              hipStream_t stream) {
    const float* x    = (const float*)d_in[0];
    const float* gW   = (const float*)d_in[1];
    const float* gb   = (const float*)d_in[2];
    const float* W1   = (const float*)d_in[3];
    const float* b1   = (const float*)d_in[4];
    const float* W2   = (const float*)d_in[5];
    const float* b2   = (const float*)d_in[6];
    const float* sW1  = (const float*)d_in[7];
    const float* sb1  = (const float*)d_in[8];
    const float* sW2  = (const float*)d_in[9];
    const float* sb2  = (const float*)d_in[10];
    const float* ebias = (const float*)d_in[11];
    float* out = (float*)d_out;

    char* w = (char*)d_ws;
    size_t off = 0;
    auto alloc = [&](size_t bytes) -> void* {
        void* p = w + off;
        off += (bytes + 255) & ~(size_t)255;
        return p;
    };
    u16* xbf   = (u16*)alloc((size_t)NTOK * DD * 2);
    u16* w1t   = (u16*)alloc((size_t)EE * HH * DD * 2);
    u16* w2t   = (u16*)alloc((size_t)EE * DD * HH * 2);
    u16* sw1t  = (u16*)alloc((size_t)HH * DD * 2);
    u16* sw2t  = (u16*)alloc((size_t)DD * HH * 2);
    int* topi  = (int*)alloc((size_t)NTOK * 3 * 4);
    float* topw = (float*)alloc((size_t)NTOK * 3 * 4);
    int* counts = (int*)alloc(128);
    float* psum = (float*)alloc(128);
    int* cursor = (int*)alloc(128);
    int* offs   = (int*)alloc(128);
    int* rowTok = (int*)alloc((size_t)MAXROWS * 4);
    float* rowW = (float*)alloc((size_t)MAXROWS * 4);
    Tile* tiles = (Tile*)alloc((size_t)MAXTILES * sizeof(Tile));
    int* numTiles = (int*)alloc(128);

    size_t fixed = off;
    size_t remain = (ws_size > fixed) ? (ws_size - fixed) : 0;
    long hr = (long)(remain / ((size_t)HH * 2));
    if (hr > MAXROWS) hr = MAXROWS;
    hr &= ~(long)255;                 // chunk boundary aligns to 256-row tiles
    if (hr < 256) hr = 256;
    int hrows = (int)hr;
    int passes = (MAXROWS + hrows - 1) / hrows;
    u16* hbuf = (u16*)(w + fixed);

    hipMemsetAsync(d_out, 0, (size_t)NTOK * DD * 4, stream);
    hipMemsetAsync(counts, 0, 768, stream);

    k_gate<<<NTOK, 256, 0, stream>>>(x, gW, gb, ebias, topi, topw, counts, psum, xbf);
    // W1 transpose LAST before gemm1 (w1t L3-fresh, r15); W2 between the GEMMs.
    k_transpose<<<dim3(512, EE + 1), 256, 0, stream>>>(W1, w1t, sW1, sw1t, 1);
    k_setup<<<1, 64, 0, stream>>>(counts, psum, offs, tiles, numTiles, out + (size_t)NTOK * DD);
    k_scatter<<<NTOK / 256, 256, 0, stream>>>(topi, topw, offs, cursor, rowTok, rowW);

    for (int p = 0; p < passes; p++) {
        k_gemm1<<<MAXTILES * (HH / BN), 256, 0, stream>>>(
            xbf, w1t, sw1t, b1, sb1, rowTok, tiles, numTiles, hbuf, p * hrows, hrows);
        if (p == 0)
            k_transpose<<<dim3(512, EE + 1), 256, 0, stream>>>(W2, w2t, sW2, sw2t, 0);
        k_gemm2<<<MAXTILES * (DD / BN), 256, 0, stream>>>(
            hbuf, w2t, sw2t, b2, sb2, rowTok, rowW, tiles, numTiles, out, p * hrows, hrows);
    }
}

// Round 18
// 1446.190 us; speedup vs baseline: 1.6735x; 1.6735x over previous
//
#include <hip/hip_runtime.h>
#include <math.h>

#define DD 1024
#define HH 4096
#define EE 23
#define KK 3
#define NTOK 8192
#define BM 128
#define BN 128
#define BK 32
#define MAXROWS 35712    // 8192 shared + 24576 routed + per-expert pad(<=23*127), rounded to 128
#define MAXTILES 280

typedef unsigned short u16;
typedef __attribute__((ext_vector_type(8))) short bf16x8;
typedef __attribute__((ext_vector_type(8))) unsigned short u16x8;
typedef __attribute__((ext_vector_type(4))) float f32x4;
typedef __attribute__((address_space(3))) unsigned int lds_u32;
typedef const __attribute__((address_space(1))) unsigned int gbl_u32;

struct Tile { int rowStart; int validEnd; int expert; };

__device__ __forceinline__ u16 f2bf(float f) {
    unsigned int u = __float_as_uint(f);
    unsigned int r = 0x7FFFu + ((u >> 16) & 1u);
    return (u16)((u + r) >> 16);
}
// exact-GELU via Abramowitz-Stegun 7.1.26 erf (max |err| 1.5e-7; fast VALU vs
// libm erff's branchy ~50 instrs). gelu(x) = 0.5 x (1 + erf(x/sqrt2)).
__device__ __forceinline__ float gelu_exact(float x) {
    float z = x * 0.70710678118654752f;
    float a = fabsf(z);
    float t = __builtin_amdgcn_rcpf(1.0f + 0.3275911f * a);
    float e = __builtin_amdgcn_exp2f(-a * a * 1.4426950408889634f);
    float p = t * (0.254829592f + t * (-0.284496736f + t * (1.421413741f +
              t * (-1.453152027f + t * 1.061405429f))));
    float er = 1.0f - p * e;
    er = (z < 0.0f) ? -er : er;
    return 0.5f * x * (1.0f + er);
}
// async global->LDS, 16B per lane. dest must be linear: base + lane*16 within
// wave. offset literal MUST stay 0 (r7: offset:64 displaced the LDS dest -> NaN).
__device__ __forceinline__ void gl2lds16(const u16* g, u16* l) {
    __builtin_amdgcn_global_load_lds((gbl_u32*)g, (lds_u32*)l, 16, 0, 0);
}

// ---- W transpose: fp32 [R][C] -> bf16 [C][R], 64x128 tiles, 16B stores ----
// which==1: W1 (runs right before gemm1 -> w1t L3-fresh; r15: -70us);
// which==0: W2 (runs between gemm1 and gemm2). fp32 reads NON-TEMPORAL.
__global__ __launch_bounds__(256) void k_transpose(
    const float* __restrict__ WE, u16* __restrict__ wEt,
    const float* __restrict__ WS, u16* __restrict__ wSt, int which) {
    __shared__ float tile[64][129];
    int f = blockIdx.y, t = threadIdx.x, b = blockIdx.x;
    const float* src; u16* dst; int R, C, ct, rt;
    if (which) {
        R = DD; C = HH;
        ct = b & 31; rt = b >> 5;
    } else {
        R = HH; C = DD;
        ct = b & 7; rt = b >> 3;
    }
    if (f == EE) { src = WS; dst = wSt; }
    else { size_t base = (size_t)f * DD * HH; src = WE + base; dst = wEt + base; }
    int r0 = rt * 64, c0 = ct * 128;
#pragma unroll
    for (int i = 0; i < 8; i++) {
        int r = i * 8 + (t >> 5);
        int c = (t & 31) * 4;
        f32x4 v = __builtin_nontemporal_load(
            reinterpret_cast<const f32x4*>(&src[(size_t)(r0 + r) * C + c0 + c]));
        tile[r][c] = v.x; tile[r][c + 1] = v.y; tile[r][c + 2] = v.z; tile[r][c + 3] = v.w;
    }
    __syncthreads();
#pragma unroll
    for (int j = 0; j < 4; j++) {
        int c = j * 32 + (t >> 3);
        int r8 = (t & 7) * 8;
        u16x8 o;
#pragma unroll
        for (int k = 0; k < 8; k++) o[k] = f2bf(tile[r8 + k][c]);
        *reinterpret_cast<u16x8*>(&dst[(size_t)(c0 + c) * R + r0 + r8]) = o;
    }
}

// -------- gating: sigmoid(x@gW+gb), top3, counts/Psum; also emits xbf --------
__global__ void k_gate(const float* __restrict__ x, const float* __restrict__ gW,
                       const float* __restrict__ gb, const float* __restrict__ ebias,
                       int* __restrict__ topi, float* __restrict__ topw,
                       int* __restrict__ counts, float* __restrict__ psum,
                       u16* __restrict__ xbf) {
    int tok = blockIdx.x, t = threadIdx.x;
    float acc[EE];
#pragma unroll
    for (int e = 0; e < EE; e++) acc[e] = 0.f;
    float4 xv = reinterpret_cast<const float4*>(x + (size_t)tok * DD)[t];
    ushort4 xo;
    xo.x = f2bf(xv.x); xo.y = f2bf(xv.y); xo.z = f2bf(xv.z); xo.w = f2bf(xv.w);
    reinterpret_cast<ushort4*>(xbf + (size_t)tok * DD)[t] = xo;
    float xs[4] = {xv.x, xv.y, xv.z, xv.w};
#pragma unroll
    for (int i = 0; i < 4; i++) {
        const float* grow = gW + (size_t)(t * 4 + i) * EE;
        float xd = xs[i];
#pragma unroll
        for (int e = 0; e < EE; e++) acc[e] += xd * grow[e];
    }
#pragma unroll
    for (int e = 0; e < EE; e++) {
        float v = acc[e];
        for (int off = 32; off; off >>= 1) v += __shfl_down(v, off);
        acc[e] = v;
    }
    __shared__ float part[4][EE];
    __shared__ float gwS[EE], scoreS[EE], rowsumS;
    int wave = t >> 6, lane = t & 63;
    if (lane == 0) {
#pragma unroll
        for (int e = 0; e < EE; e++) part[wave][e] = acc[e];
    }
    __syncthreads();
    if (t < EE) {
        float v = part[0][t] + part[1][t] + part[2][t] + part[3][t] + gb[t];
        float g = 1.f / (1.f + expf(-v));
        gwS[t] = g;
        scoreS[t] = g + ebias[t];
    }
    __syncthreads();
    if (t == 0) {
        int i0 = 0, i1 = -1, i2 = -1;
        float s0 = -1e30f, s1 = -1e30f, s2 = -1e30f;
        for (int e = 0; e < EE; e++) {
            float s = scoreS[e];
            if (s > s0)      { s2 = s1; i2 = i1; s1 = s0; i1 = i0; s0 = s; i0 = e; }
            else if (s > s1) { s2 = s1; i2 = i1; s1 = s;  i1 = e; }
            else if (s > s2) { s2 = s;  i2 = e; }
        }
        float w0 = gwS[i0], w1 = gwS[i1], w2 = gwS[i2];
        float wsum = w0 + w1 + w2;
        topi[tok * 3] = i0; topi[tok * 3 + 1] = i1; topi[tok * 3 + 2] = i2;
        topw[tok * 3] = w0 / wsum; topw[tok * 3 + 1] = w1 / wsum; topw[tok * 3 + 2] = w2 / wsum;
        atomicAdd(&counts[i0], 1); atomicAdd(&counts[i1], 1); atomicAdd(&counts[i2], 1);
        float rs = 0.f;
        for (int e = 0; e < EE; e++) rs += gwS[e];
        rowsumS = rs;
    }
    __syncthreads();
    if (t < EE) atomicAdd(&psum[t], gwS[t] / rowsumS);
}

// ---------------- offsets, tile table, aux loss (single thread) ----------------
__global__ void k_setup(const int* __restrict__ counts, const float* __restrict__ psum,
                        int* __restrict__ offs, Tile* __restrict__ tiles,
                        int* __restrict__ numTiles, float* __restrict__ out_aux) {
    if (threadIdx.x != 0 || blockIdx.x != 0) return;
    int nt = 0;
    for (int i = 0; i < NTOK / BM; i++) {
        tiles[nt].rowStart = i * BM; tiles[nt].validEnd = NTOK; tiles[nt].expert = EE; nt++;
    }
    int base = NTOK;
    for (int e = 0; e < EE; e++) {
        offs[e] = base;
        int c = counts[e];
        int ntile = (c + BM - 1) / BM;
        for (int i = 0; i < ntile; i++) {
            tiles[nt].rowStart = base + i * BM; tiles[nt].validEnd = base + c; tiles[nt].expert = e; nt++;
        }
        base += ntile * BM;
    }
    numTiles[0] = nt;
    float aux = 0.f;
    for (int e = 0; e < EE; e++)
        aux += (psum[e] / (float)NTOK) * ((float)EE * (float)counts[e] / ((float)KK * (float)NTOK));
    out_aux[0] = aux;
}

// ---------------- scatter tokens into expert row slots ----------------
__global__ void k_scatter(const int* __restrict__ topi, const float* __restrict__ topw,
                          const int* __restrict__ offs, int* __restrict__ cursor,
                          int* __restrict__ rowTok, float* __restrict__ rowW) {
    int tok = blockIdx.x * blockDim.x + threadIdx.x;
    if (tok >= NTOK) return;
    rowTok[tok] = tok; rowW[tok] = 1.0f;
    for (int k = 0; k < KK; k++) {
        int e = topi[tok * 3 + k];
        int pos = atomicAdd(&cursor[e], 1);
        int slot = offs[e] + pos;
        rowTok[slot] = tok; rowW[slot] = topw[tok * 3 + k];
    }
}

// ------- GEMM1: H = gelu(X @ W1 + b1)  [r3/r10-proven simple 2-barrier loop] -------
__global__ __launch_bounds__(256) void k_gemm1(
    const u16* __restrict__ xbf, const u16* __restrict__ w1t, const u16* __restrict__ sw1t,
    const float* __restrict__ b1, const float* __restrict__ sb1,
    const int* __restrict__ rowTok, const Tile* __restrict__ tiles,
    const int* __restrict__ numTiles, u16* __restrict__ hbuf, int chunkBase, int hrows) {
    // flatten -> XCD-bijective chunk -> supertile decode (8 tiles x 4 panels)
    const int T = MAXTILES * (HH / BN);          // 8960, %8==0
    int b = blockIdx.x;
    int key = (b & 7) * (T >> 3) + (b >> 3);
    int sid = key >> 5, wi = key & 31;           // 32 blocks per supertile
    int ti = (sid >> 3) * 8 + (wi >> 2);
    int p  = ((sid & 7) << 2) + (wi & 3);
    if (ti >= numTiles[0]) return;
    Tile tl = tiles[ti];
    if (tl.rowStart < chunkBase || tl.rowStart >= chunkBase + hrows) return;
    int e = tl.expert;
    const u16* wbase = (e == EE) ? sw1t : (w1t + (size_t)e * HH * DD);
    const float* bias = (e == EE) ? sb1 : (b1 + (size_t)e * HH);
    int hbase = p * BN;
    int t = threadIdx.x, lane = t & 63, wv = t >> 6, wr = wv >> 1, wc = wv & 1;

    __shared__ u16 As[BM * BK];   // linear [128][32]
    __shared__ u16 Bs[BN * BK];

    int rbase = wv * 16 + (lane >> 2);
    int c8 = (lane & 3) * 8;
    int s0 = tl.rowStart + rbase, s1 = s0 + 64;
    int tA0 = (s0 < tl.validEnd) ? rowTok[s0] : 0;
    int tA1 = (s1 < tl.validEnd) ? rowTok[s1] : 0;
    const u16* a0 = xbf + (size_t)tA0 * DD + c8;
    const u16* a1 = xbf + (size_t)tA1 * DD + c8;
    const u16* g0 = wbase + (size_t)(hbase + rbase) * DD + c8;
    const u16* g1 = wbase + (size_t)(hbase + 64 + rbase) * DD + c8;
    u16* lA = &As[t * 8];         // t*16 bytes
    u16* lB = &Bs[t * 8];

    f32x4 acc[4][4];
#pragma unroll
    for (int m = 0; m < 4; m++)
#pragma unroll
        for (int n = 0; n < 4; n++) acc[m][n] = (f32x4){0.f, 0.f, 0.f, 0.f};

    for (int kt = 0; kt < DD / BK; kt++) {
        __syncthreads();                       // all waves done reading previous tile
        gl2lds16(a0, lA); gl2lds16(a1, lA + 2048);
        gl2lds16(g0, lB); gl2lds16(g1, lB + 2048);
        a0 += BK; a1 += BK; g0 += BK; g1 += BK;
        __syncthreads();                       // drains vmcnt(0): LDS tile ready
        bf16x8 af[4], bw[4];
#pragma unroll
        for (int m = 0; m < 4; m++)
            af[m] = *reinterpret_cast<const bf16x8*>(&As[(wr * 64 + m * 16 + (lane & 15)) * BK + (lane >> 4) * 8]);
#pragma unroll
        for (int n = 0; n < 4; n++)
            bw[n] = *reinterpret_cast<const bf16x8*>(&Bs[(wc * 64 + n * 16 + (lane & 15)) * BK + (lane >> 4) * 8]);
#pragma unroll
        for (int m = 0; m < 4; m++)
#pragma unroll
            for (int n = 0; n < 4; n++)
                acc[m][n] = __builtin_amdgcn_mfma_f32_16x16x32_bf16(af[m], bw[n], acc[m][n], 0, 0, 0);
    }

    // epilogue: PLAIN hbuf stores (r18 isolation: drop nt-store so the freshest
    // ~85% of hbuf stays L3-resident into gemm2's A-side drains).
#pragma unroll
    for (int m = 0; m < 4; m++) {
        int rowl = wr * 64 + m * 16 + (lane >> 4) * 4;
#pragma unroll
        for (int r = 0; r < 4; r++) {
            int slotr = tl.rowStart + rowl + r;
            bool valid = slotr < tl.validEnd;
            size_t hoff = (size_t)(slotr - chunkBase) * HH;
#pragma unroll
            for (int n = 0; n < 4; n++) {
                int col = hbase + wc * 64 + n * 16 + (lane & 15);
                float v = acc[m][n][r] + bias[col];
                hbuf[hoff + col] = valid ? f2bf(gelu_exact(v)) : (u16)0;
            }
        }
    }
}

// ------- GEMM2: out += w * (H @ W2 + b2)  [r3/r10-proven simple 2-barrier loop] -------
__global__ __launch_bounds__(256) void k_gemm2(
    const u16* __restrict__ hbuf, const u16* __restrict__ w2t, const u16* __restrict__ sw2t,
    const float* __restrict__ b2, const float* __restrict__ sb2,
    const int* __restrict__ rowTok, const float* __restrict__ rowW,
    const Tile* __restrict__ tiles, const int* __restrict__ numTiles,
    float* __restrict__ out, int chunkBase, int hrows) {
    // flatten -> XCD-bijective chunk -> supertile decode (2 tiles x 2 panels)
    const int T = MAXTILES * (DD / BN);          // 2240, %8==0
    int b = blockIdx.x;
    int key = (b & 7) * (T >> 3) + (b >> 3);
    int sid = key >> 2, wi = key & 3;            // 4 blocks per supertile
    int ti = (sid >> 2) * 2 + (wi >> 1);
    int p  = ((sid & 3) << 1) + (wi & 1);
    if (ti >= numTiles[0]) return;
    Tile tl = tiles[ti];
    if (tl.rowStart < chunkBase || tl.rowStart >= chunkBase + hrows) return;
    int e = tl.expert;
    const u16* wbase = (e == EE) ? sw2t : (w2t + (size_t)e * DD * HH);
    const float* bias = (e == EE) ? sb2 : (b2 + (size_t)e * DD);
    int dbase = p * BN;
    int t = threadIdx.x, lane = t & 63, wv = t >> 6, wr = wv >> 1, wc = wv & 1;

    __shared__ u16 As[BM * BK];
    __shared__ u16 Bs[BN * BK];

    int rbase = wv * 16 + (lane >> 2);
    int c8 = (lane & 3) * 8;
    const u16* a0 = hbuf + (size_t)(tl.rowStart - chunkBase + rbase) * HH + c8;
    const u16* a1 = hbuf + (size_t)(tl.rowStart - chunkBase + 64 + rbase) * HH + c8;
    const u16* g0 = wbase + (size_t)(dbase + rbase) * HH + c8;
    const u16* g1 = wbase + (size_t)(dbase + 64 + rbase) * HH + c8;
    u16* lA = &As[t * 8];
    u16* lB = &Bs[t * 8];

    f32x4 acc[4][4];
#pragma unroll
    for (int m = 0; m < 4; m++)
#pragma unroll
        for (int n = 0; n < 4; n++) acc[m][n] = (f32x4){0.f, 0.f, 0.f, 0.f};

    for (int kt = 0; kt < HH / BK; kt++) {
        __syncthreads();
        gl2lds16(a0, lA); gl2lds16(a1, lA + 2048);
        gl2lds16(g0, lB); gl2lds16(g1, lB + 2048);
        a0 += BK; a1 += BK; g0 += BK; g1 += BK;
        __syncthreads();
        bf16x8 af[4], bw[4];
#pragma unroll
        for (int m = 0; m < 4; m++)
            af[m] = *reinterpret_cast<const bf16x8*>(&As[(wr * 64 + m * 16 + (lane & 15)) * BK + (lane >> 4) * 8]);
#pragma unroll
        for (int n = 0; n < 4; n++)
            bw[n] = *reinterpret_cast<const bf16x8*>(&Bs[(wc * 64 + n * 16 + (lane & 15)) * BK + (lane >> 4) * 8]);
#pragma unroll
        for (int m = 0; m < 4; m++)
#pragma unroll
            for (int n = 0; n < 4; n++)
                acc[m][n] = __builtin_amdgcn_mfma_f32_16x16x32_bf16(af[m], bw[n], acc[m][n], 0, 0, 0);
    }

#pragma unroll
    for (int m = 0; m < 4; m++) {
        int rowl = wr * 64 + m * 16 + (lane >> 4) * 4;
#pragma unroll
        for (int r = 0; r < 4; r++) {
            int slotr = tl.rowStart + rowl + r;
            if (slotr < tl.validEnd) {
                int tok2 = rowTok[slotr];
                float wgt = rowW[slotr];
                float* orow = out + (size_t)tok2 * DD;
#pragma unroll
                for (int n = 0; n < 4; n++) {
                    int col = dbase + wc * 64 + n * 16 + (lane & 15);
                    float v = acc[m][n][r] + bias[col];
                    atomicAdd(&orow[col], wgt * v);
                }
            }
        }
    }
}

extern "C" void kernel_launch(void* const* d_in, const int* in_sizes, int n_in,
                              void* d_out, int out_size, void* d_ws, size_t ws_size,
                              hipStream_t stream) {
    const float* x    = (const float*)d_in[0];
    const float* gW   = (const float*)d_in[1];
    const float* gb   = (const float*)d_in[2];
    const float* W1   = (const float*)d_in[3];
    const float* b1   = (const float*)d_in[4];
    const float* W2   = (const float*)d_in[5];
    const float* b2   = (const float*)d_in[6];
    const float* sW1  = (const float*)d_in[7];
    const float* sb1  = (const float*)d_in[8];
    const float* sW2  = (const float*)d_in[9];
    const float* sb2  = (const float*)d_in[10];
    const float* ebias = (const float*)d_in[11];
    float* out = (float*)d_out;

    char* w = (char*)d_ws;
    size_t off = 0;
    auto alloc = [&](size_t bytes) -> void* {
        void* p = w + off;
        off += (bytes + 255) & ~(size_t)255;
        return p;
    };
    u16* xbf   = (u16*)alloc((size_t)NTOK * DD * 2);
    u16* w1t   = (u16*)alloc((size_t)EE * HH * DD * 2);
    u16* w2t   = (u16*)alloc((size_t)EE * DD * HH * 2);
    u16* sw1t  = (u16*)alloc((size_t)HH * DD * 2);
    u16* sw2t  = (u16*)alloc((size_t)DD * HH * 2);
    int* topi  = (int*)alloc((size_t)NTOK * 3 * 4);
    float* topw = (float*)alloc((size_t)NTOK * 3 * 4);
    int* counts = (int*)alloc(128);
    float* psum = (float*)alloc(128);
    int* cursor = (int*)alloc(128);
    int* offs   = (int*)alloc(128);
    int* rowTok = (int*)alloc((size_t)MAXROWS * 4);
    float* rowW = (float*)alloc((size_t)MAXROWS * 4);
    Tile* tiles = (Tile*)alloc((size_t)MAXTILES * sizeof(Tile));
    int* numTiles = (int*)alloc(128);

    size_t fixed = off;
    size_t remain = (ws_size > fixed) ? (ws_size - fixed) : 0;
    long hr = (long)(remain / ((size_t)HH * 2));
    if (hr > MAXROWS) hr = MAXROWS;
    hr &= ~(long)127;
    if (hr < 128) hr = 128;
    int hrows = (int)hr;
    int passes = (MAXROWS + hrows - 1) / hrows;
    u16* hbuf = (u16*)(w + fixed);

    hipMemsetAsync(d_out, 0, (size_t)NTOK * DD * 4, stream);
    hipMemsetAsync(counts, 0, 768, stream);

    k_gate<<<NTOK, 256, 0, stream>>>(x, gW, gb, ebias, topi, topw, counts, psum, xbf);
    // W1 transpose LAST before gemm1 (w1t L3-fresh, r15); W2 between the GEMMs.
    k_transpose<<<dim3(512, EE + 1), 256, 0, stream>>>(W1, w1t, sW1, sw1t, 1);
    k_setup<<<1, 64, 0, stream>>>(counts, psum, offs, tiles, numTiles, out + (size_t)NTOK * DD);
    k_scatter<<<NTOK / 256, 256, 0, stream>>>(topi, topw, offs, cursor, rowTok, rowW);

    for (int p = 0; p < passes; p++) {
        k_gemm1<<<MAXTILES * (HH / BN), 256, 0, stream>>>(
            xbf, w1t, sw1t, b1, sb1, rowTok, tiles, numTiles, hbuf, p * hrows, hrows);
        if (p == 0)
            k_transpose<<<dim3(512, EE + 1), 256, 0, stream>>>(W2, w2t, sW2, sw2t, 0);
        k_gemm2<<<MAXTILES * (DD / BN), 256, 0, stream>>>(
            hbuf, w2t, sw2t, b2, sb2, rowTok, rowW, tiles, numTiles, out, p * hrows, hrows);
    }
}

// Round 19
// 1388.571 us; speedup vs baseline: 1.7430x; 1.0415x over previous
//
#include <hip/hip_runtime.h>
#include <math.h>

#define DD 1024
#define HH 4096
#define EE 23
#define KK 3
#define NTOK 8192
#define BM 128
#define BN 128
#define BK 32
#define MAXROWS 35712    // 8192 shared + 24576 routed + per-expert pad(<=23*127), rounded to 128
#define MAXTILES 280

typedef unsigned short u16;
typedef __attribute__((ext_vector_type(8))) short bf16x8;
typedef __attribute__((ext_vector_type(8))) unsigned short u16x8;
typedef __attribute__((ext_vector_type(4))) float f32x4;
typedef __attribute__((address_space(3))) unsigned int lds_u32;
typedef const __attribute__((address_space(1))) unsigned int gbl_u32;

struct Tile { int rowStart; int validEnd; int expert; };

__device__ __forceinline__ u16 f2bf(float f) {
    unsigned int u = __float_as_uint(f);
    unsigned int r = 0x7FFFu + ((u >> 16) & 1u);
    return (u16)((u + r) >> 16);
}
// exact-GELU via Abramowitz-Stegun 7.1.26 erf (max |err| 1.5e-7; fast VALU vs
// libm erff's branchy ~50 instrs). gelu(x) = 0.5 x (1 + erf(x/sqrt2)).
__device__ __forceinline__ float gelu_exact(float x) {
    float z = x * 0.70710678118654752f;
    float a = fabsf(z);
    float t = __builtin_amdgcn_rcpf(1.0f + 0.3275911f * a);
    float e = __builtin_amdgcn_exp2f(-a * a * 1.4426950408889634f);
    float p = t * (0.254829592f + t * (-0.284496736f + t * (1.421413741f +
              t * (-1.453152027f + t * 1.061405429f))));
    float er = 1.0f - p * e;
    er = (z < 0.0f) ? -er : er;
    return 0.5f * x * (1.0f + er);
}
// async global->LDS, 16B per lane. dest must be linear: base + lane*16 within
// wave. offset literal MUST stay 0 (r7: offset:64 displaced the LDS dest -> NaN).
__device__ __forceinline__ void gl2lds16(const u16* g, u16* l) {
    __builtin_amdgcn_global_load_lds((gbl_u32*)g, (lds_u32*)l, 16, 0, 0);
}

// ---- W transpose: fp32 [R][C] -> bf16 [C][R], 64x128 tiles, 16B stores ----
// which==1: W1 (runs right before gemm1 -> w1t L3-fresh; r15: -70us);
// which==0: W2 (runs between gemm1 and gemm2). fp32 reads NON-TEMPORAL.
__global__ __launch_bounds__(256) void k_transpose(
    const float* __restrict__ WE, u16* __restrict__ wEt,
    const float* __restrict__ WS, u16* __restrict__ wSt, int which) {
    __shared__ float tile[64][129];
    int f = blockIdx.y, t = threadIdx.x, b = blockIdx.x;
    const float* src; u16* dst; int R, C, ct, rt;
    if (which) {
        R = DD; C = HH;
        ct = b & 31; rt = b >> 5;
    } else {
        R = HH; C = DD;
        ct = b & 7; rt = b >> 3;
    }
    if (f == EE) { src = WS; dst = wSt; }
    else { size_t base = (size_t)f * DD * HH; src = WE + base; dst = wEt + base; }
    int r0 = rt * 64, c0 = ct * 128;
#pragma unroll
    for (int i = 0; i < 8; i++) {
        int r = i * 8 + (t >> 5);
        int c = (t & 31) * 4;
        f32x4 v = __builtin_nontemporal_load(
            reinterpret_cast<const f32x4*>(&src[(size_t)(r0 + r) * C + c0 + c]));
        tile[r][c] = v.x; tile[r][c + 1] = v.y; tile[r][c + 2] = v.z; tile[r][c + 3] = v.w;
    }
    __syncthreads();
#pragma unroll
    for (int j = 0; j < 4; j++) {
        int c = j * 32 + (t >> 3);
        int r8 = (t & 7) * 8;
        u16x8 o;
#pragma unroll
        for (int k = 0; k < 8; k++) o[k] = f2bf(tile[r8 + k][c]);
        *reinterpret_cast<u16x8*>(&dst[(size_t)(c0 + c) * R + r0 + r8]) = o;
    }
}

// -------- gating: sigmoid(x@gW+gb), top3, counts/Psum; also emits xbf --------
__global__ void k_gate(const float* __restrict__ x, const float* __restrict__ gW,
                       const float* __restrict__ gb, const float* __restrict__ ebias,
                       int* __restrict__ topi, float* __restrict__ topw,
                       int* __restrict__ counts, float* __restrict__ psum,
                       u16* __restrict__ xbf) {
    int tok = blockIdx.x, t = threadIdx.x;
    float acc[EE];
#pragma unroll
    for (int e = 0; e < EE; e++) acc[e] = 0.f;
    float4 xv = reinterpret_cast<const float4*>(x + (size_t)tok * DD)[t];
    ushort4 xo;
    xo.x = f2bf(xv.x); xo.y = f2bf(xv.y); xo.z = f2bf(xv.z); xo.w = f2bf(xv.w);
    reinterpret_cast<ushort4*>(xbf + (size_t)tok * DD)[t] = xo;
    float xs[4] = {xv.x, xv.y, xv.z, xv.w};
#pragma unroll
    for (int i = 0; i < 4; i++) {
        const float* grow = gW + (size_t)(t * 4 + i) * EE;
        float xd = xs[i];
#pragma unroll
        for (int e = 0; e < EE; e++) acc[e] += xd * grow[e];
    }
#pragma unroll
    for (int e = 0; e < EE; e++) {
        float v = acc[e];
        for (int off = 32; off; off >>= 1) v += __shfl_down(v, off);
        acc[e] = v;
    }
    __shared__ float part[4][EE];
    __shared__ float gwS[EE], scoreS[EE], rowsumS;
    int wave = t >> 6, lane = t & 63;
    if (lane == 0) {
#pragma unroll
        for (int e = 0; e < EE; e++) part[wave][e] = acc[e];
    }
    __syncthreads();
    if (t < EE) {
        float v = part[0][t] + part[1][t] + part[2][t] + part[3][t] + gb[t];
        float g = 1.f / (1.f + expf(-v));
        gwS[t] = g;
        scoreS[t] = g + ebias[t];
    }
    __syncthreads();
    if (t == 0) {
        int i0 = 0, i1 = -1, i2 = -1;
        float s0 = -1e30f, s1 = -1e30f, s2 = -1e30f;
        for (int e = 0; e < EE; e++) {
            float s = scoreS[e];
            if (s > s0)      { s2 = s1; i2 = i1; s1 = s0; i1 = i0; s0 = s; i0 = e; }
            else if (s > s1) { s2 = s1; i2 = i1; s1 = s;  i1 = e; }
            else if (s > s2) { s2 = s;  i2 = e; }
        }
        float w0 = gwS[i0], w1 = gwS[i1], w2 = gwS[i2];
        float wsum = w0 + w1 + w2;
        topi[tok * 3] = i0; topi[tok * 3 + 1] = i1; topi[tok * 3 + 2] = i2;
        topw[tok * 3] = w0 / wsum; topw[tok * 3 + 1] = w1 / wsum; topw[tok * 3 + 2] = w2 / wsum;
        atomicAdd(&counts[i0], 1); atomicAdd(&counts[i1], 1); atomicAdd(&counts[i2], 1);
        float rs = 0.f;
        for (int e = 0; e < EE; e++) rs += gwS[e];
        rowsumS = rs;
    }
    __syncthreads();
    if (t < EE) atomicAdd(&psum[t], gwS[t] / rowsumS);
}

// ---------------- offsets, tile table, aux loss (single thread) ----------------
__global__ void k_setup(const int* __restrict__ counts, const float* __restrict__ psum,
                        int* __restrict__ offs, Tile* __restrict__ tiles,
                        int* __restrict__ numTiles, float* __restrict__ out_aux) {
    if (threadIdx.x != 0 || blockIdx.x != 0) return;
    int nt = 0;
    for (int i = 0; i < NTOK / BM; i++) {
        tiles[nt].rowStart = i * BM; tiles[nt].validEnd = NTOK; tiles[nt].expert = EE; nt++;
    }
    int base = NTOK;
    for (int e = 0; e < EE; e++) {
        offs[e] = base;
        int c = counts[e];
        int ntile = (c + BM - 1) / BM;
        for (int i = 0; i < ntile; i++) {
            tiles[nt].rowStart = base + i * BM; tiles[nt].validEnd = base + c; tiles[nt].expert = e; nt++;
        }
        base += ntile * BM;
    }
    numTiles[0] = nt;
    float aux = 0.f;
    for (int e = 0; e < EE; e++)
        aux += (psum[e] / (float)NTOK) * ((float)EE * (float)counts[e] / ((float)KK * (float)NTOK));
    out_aux[0] = aux;
}

// ---------------- scatter tokens into expert row slots ----------------
__global__ void k_scatter(const int* __restrict__ topi, const float* __restrict__ topw,
                          const int* __restrict__ offs, int* __restrict__ cursor,
                          int* __restrict__ rowTok, float* __restrict__ rowW) {
    int tok = blockIdx.x * blockDim.x + threadIdx.x;
    if (tok >= NTOK) return;
    rowTok[tok] = tok; rowW[tok] = 1.0f;
    for (int k = 0; k < KK; k++) {
        int e = topi[tok * 3 + k];
        int pos = atomicAdd(&cursor[e], 1);
        int slot = offs[e] + pos;
        rowTok[slot] = tok; rowW[slot] = topw[tok * 3 + k];
    }
}

// ------- GEMM1: H = gelu(X @ W1 + b1)  [r3/r10-proven simple 2-barrier loop] -------
__global__ __launch_bounds__(256) void k_gemm1(
    const u16* __restrict__ xbf, const u16* __restrict__ w1t, const u16* __restrict__ sw1t,
    const float* __restrict__ b1, const float* __restrict__ sb1,
    const int* __restrict__ rowTok, const Tile* __restrict__ tiles,
    const int* __restrict__ numTiles, u16* __restrict__ hbuf, int chunkBase, int hrows) {
    // flatten -> XCD-bijective chunk -> supertile decode (8 tiles x 4 panels)
    const int T = MAXTILES * (HH / BN);          // 8960, %8==0
    int b = blockIdx.x;
    int key = (b & 7) * (T >> 3) + (b >> 3);
    int sid = key >> 5, wi = key & 31;           // 32 blocks per supertile
    int ti = (sid >> 3) * 8 + (wi >> 2);
    int p  = ((sid & 7) << 2) + (wi & 3);
    if (ti >= numTiles[0]) return;
    Tile tl = tiles[ti];
    if (tl.rowStart < chunkBase || tl.rowStart >= chunkBase + hrows) return;
    int e = tl.expert;
    const u16* wbase = (e == EE) ? sw1t : (w1t + (size_t)e * HH * DD);
    const float* bias = (e == EE) ? sb1 : (b1 + (size_t)e * HH);
    int hbase = p * BN;
    int t = threadIdx.x, lane = t & 63, wv = t >> 6, wr = wv >> 1, wc = wv & 1;

    __shared__ u16 As[BM * BK];   // linear [128][32]
    __shared__ u16 Bs[BN * BK];

    int rbase = wv * 16 + (lane >> 2);
    int c8 = (lane & 3) * 8;
    int s0 = tl.rowStart + rbase, s1 = s0 + 64;
    int tA0 = (s0 < tl.validEnd) ? rowTok[s0] : 0;
    int tA1 = (s1 < tl.validEnd) ? rowTok[s1] : 0;
    const u16* a0 = xbf + (size_t)tA0 * DD + c8;
    const u16* a1 = xbf + (size_t)tA1 * DD + c8;
    const u16* g0 = wbase + (size_t)(hbase + rbase) * DD + c8;
    const u16* g1 = wbase + (size_t)(hbase + 64 + rbase) * DD + c8;
    u16* lA = &As[t * 8];         // t*16 bytes
    u16* lB = &Bs[t * 8];

    f32x4 acc[4][4];
#pragma unroll
    for (int m = 0; m < 4; m++)
#pragma unroll
        for (int n = 0; n < 4; n++) acc[m][n] = (f32x4){0.f, 0.f, 0.f, 0.f};

    for (int kt = 0; kt < DD / BK; kt++) {
        __syncthreads();                       // all waves done reading previous tile
        gl2lds16(a0, lA); gl2lds16(a1, lA + 2048);
        gl2lds16(g0, lB); gl2lds16(g1, lB + 2048);
        a0 += BK; a1 += BK; g0 += BK; g1 += BK;
        __syncthreads();                       // drains vmcnt(0): LDS tile ready
        bf16x8 af[4], bw[4];
#pragma unroll
        for (int m = 0; m < 4; m++)
            af[m] = *reinterpret_cast<const bf16x8*>(&As[(wr * 64 + m * 16 + (lane & 15)) * BK + (lane >> 4) * 8]);
#pragma unroll
        for (int n = 0; n < 4; n++)
            bw[n] = *reinterpret_cast<const bf16x8*>(&Bs[(wc * 64 + n * 16 + (lane & 15)) * BK + (lane >> 4) * 8]);
#pragma unroll
        for (int m = 0; m < 4; m++)
#pragma unroll
            for (int n = 0; n < 4; n++)
                acc[m][n] = __builtin_amdgcn_mfma_f32_16x16x32_bf16(af[m], bw[n], acc[m][n], 0, 0, 0);
    }

    // epilogue: NON-TEMPORAL hbuf stores — keeps gemm1's 274MB write stream from
    // evicting the L3-resident w1t panels (r18 A/B: removing this cost +56us).
#pragma unroll
    for (int m = 0; m < 4; m++) {
        int rowl = wr * 64 + m * 16 + (lane >> 4) * 4;
#pragma unroll
        for (int r = 0; r < 4; r++) {
            int slotr = tl.rowStart + rowl + r;
            bool valid = slotr < tl.validEnd;
            size_t hoff = (size_t)(slotr - chunkBase) * HH;
#pragma unroll
            for (int n = 0; n < 4; n++) {
                int col = hbase + wc * 64 + n * 16 + (lane & 15);
                float v = acc[m][n][r] + bias[col];
                u16 o = valid ? f2bf(gelu_exact(v)) : (u16)0;
                __builtin_nontemporal_store(o, &hbuf[hoff + col]);
            }
        }
    }
}

// ------- GEMM2: out += w * (H @ W2 + b2)  [r3/r10-proven simple 2-barrier loop] -------
__global__ __launch_bounds__(256) void k_gemm2(
    const u16* __restrict__ hbuf, const u16* __restrict__ w2t, const u16* __restrict__ sw2t,
    const float* __restrict__ b2, const float* __restrict__ sb2,
    const int* __restrict__ rowTok, const float* __restrict__ rowW,
    const Tile* __restrict__ tiles, const int* __restrict__ numTiles,
    float* __restrict__ out, int chunkBase, int hrows) {
    // flatten -> XCD-bijective chunk -> supertile decode (2 tiles x 2 panels)
    const int T = MAXTILES * (DD / BN);          // 2240, %8==0
    int b = blockIdx.x;
    int key = (b & 7) * (T >> 3) + (b >> 3);
    int sid = key >> 2, wi = key & 3;            // 4 blocks per supertile
    int ti = (sid >> 2) * 2 + (wi >> 1);
    int p  = ((sid & 3) << 1) + (wi & 1);
    if (ti >= numTiles[0]) return;
    Tile tl = tiles[ti];
    if (tl.rowStart < chunkBase || tl.rowStart >= chunkBase + hrows) return;
    int e = tl.expert;
    const u16* wbase = (e == EE) ? sw2t : (w2t + (size_t)e * DD * HH);
    const float* bias = (e == EE) ? sb2 : (b2 + (size_t)e * DD);
    int dbase = p * BN;
    int t = threadIdx.x, lane = t & 63, wv = t >> 6, wr = wv >> 1, wc = wv & 1;

    __shared__ u16 As[BM * BK];
    __shared__ u16 Bs[BN * BK];

    int rbase = wv * 16 + (lane >> 2);
    int c8 = (lane & 3) * 8;
    const u16* a0 = hbuf + (size_t)(tl.rowStart - chunkBase + rbase) * HH + c8;
    const u16* a1 = hbuf + (size_t)(tl.rowStart - chunkBase + 64 + rbase) * HH + c8;
    const u16* g0 = wbase + (size_t)(dbase + rbase) * HH + c8;
    const u16* g1 = wbase + (size_t)(dbase + 64 + rbase) * HH + c8;
    u16* lA = &As[t * 8];
    u16* lB = &Bs[t * 8];

    f32x4 acc[4][4];
#pragma unroll
    for (int m = 0; m < 4; m++)
#pragma unroll
        for (int n = 0; n < 4; n++) acc[m][n] = (f32x4){0.f, 0.f, 0.f, 0.f};

    for (int kt = 0; kt < HH / BK; kt++) {
        __syncthreads();
        gl2lds16(a0, lA); gl2lds16(a1, lA + 2048);
        gl2lds16(g0, lB); gl2lds16(g1, lB + 2048);
        a0 += BK; a1 += BK; g0 += BK; g1 += BK;
        __syncthreads();
        bf16x8 af[4], bw[4];
#pragma unroll
        for (int m = 0; m < 4; m++)
            af[m] = *reinterpret_cast<const bf16x8*>(&As[(wr * 64 + m * 16 + (lane & 15)) * BK + (lane >> 4) * 8]);
#pragma unroll
        for (int n = 0; n < 4; n++)
            bw[n] = *reinterpret_cast<const bf16x8*>(&Bs[(wc * 64 + n * 16 + (lane & 15)) * BK + (lane >> 4) * 8]);
#pragma unroll
        for (int m = 0; m < 4; m++)
#pragma unroll
            for (int n = 0; n < 4; n++)
                acc[m][n] = __builtin_amdgcn_mfma_f32_16x16x32_bf16(af[m], bw[n], acc[m][n], 0, 0, 0);
    }

#pragma unroll
    for (int m = 0; m < 4; m++) {
        int rowl = wr * 64 + m * 16 + (lane >> 4) * 4;
#pragma unroll
        for (int r = 0; r < 4; r++) {
            int slotr = tl.rowStart + rowl + r;
            if (slotr < tl.validEnd) {
                int tok2 = rowTok[slotr];
                float wgt = rowW[slotr];
                float* orow = out + (size_t)tok2 * DD;
#pragma unroll
                for (int n = 0; n < 4; n++) {
                    int col = dbase + wc * 64 + n * 16 + (lane & 15);
                    float v = acc[m][n][r] + bias[col];
                    atomicAdd(&orow[col], wgt * v);
                }
            }
        }
    }
}

extern "C" void kernel_launch(void* const* d_in, const int* in_sizes, int n_in,
                              void* d_out, int out_size, void* d_ws, size_t ws_size,
                              hipStream_t stream) {
    const float* x    = (const float*)d_in[0];
    const float* gW   = (const float*)d_in[1];
    const float* gb   = (const float*)d_in[2];
    const float* W1   = (const float*)d_in[3];
    const float* b1   = (const float*)d_in[4];
    const float* W2   = (const float*)d_in[5];
    const float* b2   = (const float*)d_in[6];
    const float* sW1  = (const float*)d_in[7];
    const float* sb1  = (const float*)d_in[8];
    const float* sW2  = (const float*)d_in[9];
    const float* sb2  = (const float*)d_in[10];
    const float* ebias = (const float*)d_in[11];
    float* out = (float*)d_out;

    char* w = (char*)d_ws;
    size_t off = 0;
    auto alloc = [&](size_t bytes) -> void* {
        void* p = w + off;
        off += (bytes + 255) & ~(size_t)255;
        return p;
    };
    u16* xbf   = (u16*)alloc((size_t)NTOK * DD * 2);
    u16* w1t   = (u16*)alloc((size_t)EE * HH * DD * 2);
    u16* w2t   = (u16*)alloc((size_t)EE * DD * HH * 2);
    u16* sw1t  = (u16*)alloc((size_t)HH * DD * 2);
    u16* sw2t  = (u16*)alloc((size_t)DD * HH * 2);
    int* topi  = (int*)alloc((size_t)NTOK * 3 * 4);
    float* topw = (float*)alloc((size_t)NTOK * 3 * 4);
    int* counts = (int*)alloc(128);
    float* psum = (float*)alloc(128);
    int* cursor = (int*)alloc(128);
    int* offs   = (int*)alloc(128);
    int* rowTok = (int*)alloc((size_t)MAXROWS * 4);
    float* rowW = (float*)alloc((size_t)MAXROWS * 4);
    Tile* tiles = (Tile*)alloc((size_t)MAXTILES * sizeof(Tile));
    int* numTiles = (int*)alloc(128);

    size_t fixed = off;
    size_t remain = (ws_size > fixed) ? (ws_size - fixed) : 0;
    long hr = (long)(remain / ((size_t)HH * 2));
    if (hr > MAXROWS) hr = MAXROWS;
    hr &= ~(long)127;
    if (hr < 128) hr = 128;
    int hrows = (int)hr;
    int passes = (MAXROWS + hrows - 1) / hrows;
    u16* hbuf = (u16*)(w + fixed);

    hipMemsetAsync(d_out, 0, (size_t)NTOK * DD * 4, stream);
    hipMemsetAsync(counts, 0, 768, stream);

    k_gate<<<NTOK, 256, 0, stream>>>(x, gW, gb, ebias, topi, topw, counts, psum, xbf);
    // W1 transpose LAST before gemm1 (w1t L3-fresh, r15); W2 between the GEMMs.
    k_transpose<<<dim3(512, EE + 1), 256, 0, stream>>>(W1, w1t, sW1, sw1t, 1);
    k_setup<<<1, 64, 0, stream>>>(counts, psum, offs, tiles, numTiles, out + (size_t)NTOK * DD);
    k_scatter<<<NTOK / 256, 256, 0, stream>>>(topi, topw, offs, cursor, rowTok, rowW);

    for (int p = 0; p < passes; p++) {
        k_gemm1<<<MAXTILES * (HH / BN), 256, 0, stream>>>(
            xbf, w1t, sw1t, b1, sb1, rowTok, tiles, numTiles, hbuf, p * hrows, hrows);
        if (p == 0)
            k_transpose<<<dim3(512, EE + 1), 256, 0, stream>>>(W2, w2t, sW2, sw2t, 0);
        k_gemm2<<<MAXTILES * (DD / BN), 256, 0, stream>>>(
            hbuf, w2t, sw2t, b2, sb2, rowTok, rowW, tiles, numTiles, out, p * hrows, hrows);
    }
}